// Round 1
// baseline (8101.098 us; speedup 1.0000x reference)
//
#include <hip/hip_runtime.h>

#define NN 100000
#define NE 1600000
#define KORD 10
#define HID 64

// ---------- degree / norm build ----------
__global__ __launch_bounds__(256) void k_init_deg(float* __restrict__ deg) {
    int i = blockIdx.x * 256 + threadIdx.x;
    if (i < NN) deg[i] = 1.0f;   // self-loop contributes 1 to every node
}

__global__ __launch_bounds__(256) void k_count(const int* __restrict__ ei,
                                               float* __restrict__ deg) {
    int e = blockIdx.x * 256 + threadIdx.x;
    if (e < NE) atomicAdd(&deg[ei[NE + e]], 1.0f);   // col = ei[1][e]
}

__global__ __launch_bounds__(256) void k_dinv(float* __restrict__ d) {
    int i = blockIdx.x * 256 + threadIdx.x;
    if (i < NN) d[i] = 1.0f / sqrtf(d[i]);
}

__global__ __launch_bounds__(256) void k_edgeprep(const int* __restrict__ ei,
                                                  const float* __restrict__ dinv,
                                                  float* __restrict__ w) {
    int e = blockIdx.x * 256 + threadIdx.x;
    if (e < NE) w[e] = dinv[ei[e]] * dinv[ei[NE + e]];
}

// ---------- GEMM1: h = relu(x @ W1 + b1), x: NN x 256, W1: 256 x 64 ----------
__global__ __launch_bounds__(512) void k_gemm1(const float* __restrict__ x,
                                               const float* __restrict__ W1,
                                               const float* __restrict__ b1,
                                               float* __restrict__ h) {
    __shared__ float W1s[256 * 64];
    __shared__ float b1s[64];
    int t = threadIdx.x;
    for (int i = t * 4; i < 256 * 64; i += 512 * 4)
        *(float4*)&W1s[i] = *(const float4*)&W1[i];
    if (t < 64) b1s[t] = b1[t];
    __syncthreads();

    int wave = t >> 6, lane = t & 63;
    int row = blockIdx.x * 8 + wave;
    if (row >= NN) return;
    const float4* xr = (const float4*)(x + (size_t)row * 256);
    float acc = b1s[lane];
#pragma unroll 4
    for (int k4 = 0; k4 < 64; ++k4) {
        float4 xv = xr[k4];
        int k = k4 * 4;
        acc += xv.x * W1s[(k + 0) * 64 + lane];
        acc += xv.y * W1s[(k + 1) * 64 + lane];
        acc += xv.z * W1s[(k + 2) * 64 + lane];
        acc += xv.w * W1s[(k + 3) * 64 + lane];
    }
    h[(size_t)row * 64 + lane] = fmaxf(acc, 0.0f);
}

// ---------- propagation: dst = P * src ----------
// self-loop part: dst[i,:] = dinv[i]^2 * src[i,:]
__global__ __launch_bounds__(256) void k_selfinit(float* __restrict__ dst,
                                                  const float* __restrict__ src,
                                                  const float* __restrict__ dinv) {
    int i = blockIdx.x * 256 + threadIdx.x;
    if (i >= NN * HID) return;
    float dv = dinv[i >> 6];
    dst[i] = dv * dv * src[i];
}

// edge part: dst[col,:] += w[e] * src[row,:]  (one thread per (edge, channel))
__global__ __launch_bounds__(256) void k_edges(const int* __restrict__ ei,
                                               const float* __restrict__ w,
                                               const float* __restrict__ src,
                                               float* __restrict__ dst) {
    long gid = (long)blockIdx.x * 256 + threadIdx.x;
    if (gid >= (long)NE * HID) return;
    int e = (int)(gid >> 6), c = (int)(gid & 63);
    int r = ei[e], col = ei[NE + e];
    atomicAdd(&dst[(size_t)col * 64 + c], w[e] * src[(size_t)r * 64 + c]);
}

// ---------- combine steps ----------
// acc = c0*h + c1*t1   (t1 already holds prop(h))
__global__ __launch_bounds__(256) void k_comb1(const float* __restrict__ h,
                                               const float* __restrict__ t1,
                                               float* __restrict__ acc,
                                               const float* __restrict__ coeffs,
                                               int base) {
    int i = blockIdx.x * 256 + threadIdx.x;
    if (i >= NN * HID) return;
    float c0 = coeffs[base], c1 = coeffs[base + 1];
    acc[i] = c0 * h[i] + c1 * t1[i];
}

// t2 = An*prop + Bn*t1 - Cn*t0 (prop result is in t2); acc += ck*t2
__global__ __launch_bounds__(256) void k_comb(float* __restrict__ t2,
                                              const float* __restrict__ t1,
                                              const float* __restrict__ t0,
                                              float* __restrict__ acc,
                                              float An, float Bn, float Cn,
                                              const float* __restrict__ coeffs,
                                              int idx) {
    int i = blockIdx.x * 256 + threadIdx.x;
    if (i >= NN * HID) return;
    float v = An * t2[i] + Bn * t1[i] - Cn * t0[i];
    t2[i] = v;
    acc[i] += coeffs[idx] * v;
}

__global__ __launch_bounds__(256) void k_relu(float* __restrict__ h,
                                              const float* __restrict__ acc) {
    int i = blockIdx.x * 256 + threadIdx.x;
    if (i >= NN * HID) return;
    h[i] = fmaxf(acc[i], 0.0f);
}

// ---------- GEMM2: out = h @ W2 + b2, h: NN x 64, W2: 64 x 32 ----------
__global__ __launch_bounds__(256) void k_gemm2(const float* __restrict__ h,
                                               const float* __restrict__ W2,
                                               const float* __restrict__ b2,
                                               float* __restrict__ out) {
    __shared__ float W2s[64 * 32];
    __shared__ float b2s[32];
    int t = threadIdx.x;
    for (int i = t * 4; i < 64 * 32; i += 256 * 4)
        *(float4*)&W2s[i] = *(const float4*)&W2[i];
    if (t < 32) b2s[t] = b2[t];
    __syncthreads();

    int gid = blockIdx.x * 256 + t;
    int row = gid >> 5, c = gid & 31;
    if (row >= NN) return;
    const float* hr = h + (size_t)row * 64;
    float acc = b2s[c];
#pragma unroll
    for (int k = 0; k < 64; ++k) acc += hr[k] * W2s[k * 32 + c];
    out[(size_t)row * 32 + c] = acc;
}

extern "C" void kernel_launch(void* const* d_in, const int* in_sizes, int n_in,
                              void* d_out, int out_size, void* d_ws, size_t ws_size,
                              hipStream_t stream) {
    const float* x      = (const float*)d_in[0];
    const int*   ei     = (const int*)d_in[1];     // [2, NE] int32
    const float* W1     = (const float*)d_in[2];
    const float* b1     = (const float*)d_in[3];
    const float* coeffs = (const float*)d_in[4];   // [2, K+1]
    const float* W2     = (const float*)d_in[5];
    const float* b2     = (const float*)d_in[6];
    float* out = (float*)d_out;

    // workspace layout (floats)
    float* ws = (float*)d_ws;
    size_t off = 0;
    auto alloc = [&](size_t n) { float* p = ws + off; off += (n + 63) & ~(size_t)63; return p; };
    float* dinv = alloc(NN);
    float* wbuf = alloc(NE);
    float* h    = alloc((size_t)NN * HID);
    float* bufA = alloc((size_t)NN * HID);
    float* bufB = alloc((size_t)NN * HID);
    float* bufC = alloc((size_t)NN * HID);
    float* accb = alloc((size_t)NN * HID);

    const int BN   = (NN + 255) / 256;            // node grid
    const int BE   = (NE + 255) / 256;            // edge grid
    const int BNH  = (NN * HID + 255) / 256;      // node*feat grid
    const long ne64 = (long)NE * HID;
    const int BEH  = (int)((ne64 + 255) / 256);   // edge*feat grid

    // norm build
    k_init_deg<<<BN, 256, 0, stream>>>(dinv);
    k_count<<<BE, 256, 0, stream>>>(ei, dinv);
    k_dinv<<<BN, 256, 0, stream>>>(dinv);
    k_edgeprep<<<BE, 256, 0, stream>>>(ei, dinv, wbuf);

    // h = relu(x @ W1 + b1)
    k_gemm1<<<(NN + 7) / 8, 512, 0, stream>>>(x, W1, b1, h);

    // rotation buffers: gen k lives in rot[k & 3]; gen0 = h
    float* rot[4] = {h, bufA, bufB, bufC};

    for (int l = 0; l < 2; ++l) {
        int cbase = l * (KORD + 1);
        // k = 1: t1 = P h
        k_selfinit<<<BNH, 256, 0, stream>>>(rot[1], rot[0], dinv);
        k_edges<<<BEH, 256, 0, stream>>>(ei, wbuf, rot[0], rot[1]);
        k_comb1<<<BNH, 256, 0, stream>>>(rot[0], rot[1], accb, coeffs, cbase);

        for (int k = 2; k <= KORD; ++k) {
            float* dst = rot[k & 3];
            const float* s1 = rot[(k - 1) & 3];
            const float* s0 = rot[(k - 2) & 3];
            k_selfinit<<<BNH, 256, 0, stream>>>(dst, s1, dinv);
            k_edges<<<BEH, 256, 0, stream>>>(ei, wbuf, s1, dst);
            double n = k - 1, a = 0.5, b = 0.5;
            double An = (2*n + a + b + 1) * (2*n + a + b + 2) / (2 * (n + 1) * (n + a + b + 1));
            double Bn = (a*a - b*b) * (2*n + a + b + 1) / (2 * (n + 1) * (n + a + b + 1) * (2*n + a + b));
            double Cn = (n + a) * (n + b) * (2*n + a + b + 2) / ((n + 1) * (n + a + b + 1) * (2*n + a + b));
            k_comb<<<BNH, 256, 0, stream>>>(dst, s1, s0, accb,
                                            (float)An, (float)Bn, (float)Cn,
                                            coeffs, cbase + k);
        }
        // h = relu(acc)  (rot[0] == h; safe: last read of rot[0] was k=10's s0)
        k_relu<<<BNH, 256, 0, stream>>>(h, accb);
    }

    // out = h @ W2 + b2
    k_gemm2<<<(NN * 32 + 255) / 256, 256, 0, stream>>>(h, W2, b2, out);
}

// Round 2
// 2205.659 us; speedup vs baseline: 3.6729x; 3.6729x over previous
//
#include <hip/hip_runtime.h>

#define NN 100000
#define NE 1600000
#define KORD 10
#define HID 64
#define SCAN_BLK 1024
#define NBLK ((NN + SCAN_BLK - 1) / SCAN_BLK)   // 98

// ---------------- CSR build ----------------
__global__ __launch_bounds__(256) void k_zero(int* __restrict__ cnt) {
    int i = blockIdx.x * 256 + threadIdx.x;
    if (i < NN) cnt[i] = 0;
}

__global__ __launch_bounds__(256) void k_hist(const int* __restrict__ ei,
                                              int* __restrict__ cnt) {
    int e = blockIdx.x * 256 + threadIdx.x;
    if (e < NE) atomicAdd(&cnt[ei[NE + e]], 1);
}

__global__ __launch_bounds__(256) void k_dinv(const int* __restrict__ cnt,
                                              float* __restrict__ dinv) {
    int i = blockIdx.x * 256 + threadIdx.x;
    if (i < NN) dinv[i] = rsqrtf((float)(cnt[i] + 1));   // +1 self-loop
}

// per-block exclusive scan of cnt -> cursor, block totals -> bsum
__global__ __launch_bounds__(SCAN_BLK) void k_scan1(const int* __restrict__ cnt,
                                                    int* __restrict__ cursor,
                                                    int* __restrict__ bsum) {
    __shared__ int tmp[SCAN_BLK];
    int t = threadIdx.x;
    int g = blockIdx.x * SCAN_BLK + t;
    int v = (g < NN) ? cnt[g] : 0;
    tmp[t] = v;
    __syncthreads();
    int x = v;
    for (int off = 1; off < SCAN_BLK; off <<= 1) {
        int y = (t >= off) ? tmp[t - off] : 0;
        __syncthreads();
        x += y;
        tmp[t] = x;
        __syncthreads();
    }
    if (g < NN) cursor[g] = x - v;          // exclusive within block
    if (t == SCAN_BLK - 1) bsum[blockIdx.x] = x;
}

__global__ void k_scan2(int* __restrict__ bsum) {
    if (threadIdx.x == 0) {
        int s = 0;
        for (int i = 0; i < NBLK; ++i) { int t = bsum[i]; bsum[i] = s; s += t; }
    }
}

__global__ __launch_bounds__(SCAN_BLK) void k_scan3(int* __restrict__ cursor,
                                                    const int* __restrict__ bsum) {
    int g = blockIdx.x * SCAN_BLK + threadIdx.x;
    if (g < NN) cursor[g] += bsum[blockIdx.x];
}

// scatter edges into CSR; cursor[i] ends up as row_end[i]
__global__ __launch_bounds__(256) void k_scatter(const int* __restrict__ ei,
                                                 const float* __restrict__ dinv,
                                                 int* __restrict__ cursor,
                                                 int2* __restrict__ csr) {
    int e = blockIdx.x * 256 + threadIdx.x;
    if (e >= NE) return;
    int r = ei[e], c = ei[NE + e];
    float wv = dinv[r] * dinv[c];
    int pos = atomicAdd(&cursor[c], 1);
    csr[pos] = make_int2(r, __float_as_int(wv));
}

// ---------- GEMM1: h = relu(x @ W1 + b1), x: NN x 256, W1: 256 x 64 ----------
__global__ __launch_bounds__(512) void k_gemm1(const float* __restrict__ x,
                                               const float* __restrict__ W1,
                                               const float* __restrict__ b1,
                                               float* __restrict__ h) {
    __shared__ float W1s[256 * 64];
    __shared__ float b1s[64];
    int t = threadIdx.x;
    for (int i = t * 4; i < 256 * 64; i += 512 * 4)
        *(float4*)&W1s[i] = *(const float4*)&W1[i];
    if (t < 64) b1s[t] = b1[t];
    __syncthreads();

    int wave = t >> 6, lane = t & 63;
    int row = blockIdx.x * 8 + wave;
    if (row >= NN) return;
    const float4* xr = (const float4*)(x + (size_t)row * 256);
    float acc = b1s[lane];
#pragma unroll 4
    for (int k4 = 0; k4 < 64; ++k4) {
        float4 xv = xr[k4];
        int k = k4 * 4;
        acc += xv.x * W1s[(k + 0) * 64 + lane];
        acc += xv.y * W1s[(k + 1) * 64 + lane];
        acc += xv.z * W1s[(k + 2) * 64 + lane];
        acc += xv.w * W1s[(k + 3) * 64 + lane];
    }
    h[(size_t)row * 64 + lane] = fmaxf(acc, 0.0f);
}

// ---------- fused propagation + Jacobi combine ----------
// One wave per node, lane = channel.
//   p   = dinv[n]^2 * src[n,c] + sum_{e in CSR[n]} w_e * src[row_e, c]
//   v   = An*p + Bn*src[n,c] - Cn*t0[n,c]
//   dst[n,c] = v
//   acc[n,c] = (init ? c0*src[n,c] : acc[n,c]) + ck*v
__global__ __launch_bounds__(256) void k_prop(const int* __restrict__ cursor,   // end offsets
                                              const int2* __restrict__ csr,
                                              const float* __restrict__ src,
                                              const float* __restrict__ t0,
                                              const float* __restrict__ dinv,
                                              float* __restrict__ dst,
                                              float* __restrict__ acc,
                                              float An, float Bn, float Cn,
                                              const float* __restrict__ coeffs,
                                              int cbase, int kidx, int init) {
    int node = blockIdx.x * 4 + (threadIdx.x >> 6);
    int lane = threadIdx.x & 63;
    if (node >= NN) return;

    int beg = (node == 0) ? 0 : cursor[node - 1];
    int end = cursor[node];

    float dv = dinv[node];
    size_t idx = (size_t)node * HID + lane;
    float s = src[idx];
    float p = dv * dv * s;

    int j = beg;
    for (; j + 4 <= end; j += 4) {
        int2 e0 = csr[j], e1 = csr[j + 1], e2 = csr[j + 2], e3 = csr[j + 3];
        float g0 = src[(size_t)e0.x * HID + lane];
        float g1 = src[(size_t)e1.x * HID + lane];
        float g2 = src[(size_t)e2.x * HID + lane];
        float g3 = src[(size_t)e3.x * HID + lane];
        p += __int_as_float(e0.y) * g0;
        p += __int_as_float(e1.y) * g1;
        p += __int_as_float(e2.y) * g2;
        p += __int_as_float(e3.y) * g3;
    }
    for (; j < end; ++j) {
        int2 e = csr[j];
        p += __int_as_float(e.y) * src[(size_t)e.x * HID + lane];
    }

    float v = An * p + Bn * s - Cn * t0[idx];
    dst[idx] = v;
    float ck = coeffs[cbase + kidx];
    float a;
    if (init) a = coeffs[cbase] * s;
    else      a = acc[idx];
    acc[idx] = a + ck * v;
}

__global__ __launch_bounds__(256) void k_relu(float* __restrict__ h,
                                              const float* __restrict__ acc) {
    int i = blockIdx.x * 256 + threadIdx.x;
    if (i >= NN * HID) return;
    h[i] = fmaxf(acc[i], 0.0f);
}

// ---------- GEMM2: out = h @ W2 + b2, h: NN x 64, W2: 64 x 32 ----------
__global__ __launch_bounds__(256) void k_gemm2(const float* __restrict__ h,
                                               const float* __restrict__ W2,
                                               const float* __restrict__ b2,
                                               float* __restrict__ out) {
    __shared__ float W2s[64 * 32];
    __shared__ float b2s[32];
    int t = threadIdx.x;
    for (int i = t * 4; i < 64 * 32; i += 256 * 4)
        *(float4*)&W2s[i] = *(const float4*)&W2[i];
    if (t < 32) b2s[t] = b2[t];
    __syncthreads();

    int gid = blockIdx.x * 256 + t;
    int row = gid >> 5, c = gid & 31;
    if (row >= NN) return;
    const float* hr = h + (size_t)row * 64;
    float acc = b2s[c];
#pragma unroll
    for (int k = 0; k < 64; ++k) acc += hr[k] * W2s[k * 32 + c];
    out[(size_t)row * 32 + c] = acc;
}

extern "C" void kernel_launch(void* const* d_in, const int* in_sizes, int n_in,
                              void* d_out, int out_size, void* d_ws, size_t ws_size,
                              hipStream_t stream) {
    const float* x      = (const float*)d_in[0];
    const int*   ei     = (const int*)d_in[1];     // [2, NE] int32
    const float* W1     = (const float*)d_in[2];
    const float* b1     = (const float*)d_in[3];
    const float* coeffs = (const float*)d_in[4];   // [2, K+1]
    const float* W2     = (const float*)d_in[5];
    const float* b2     = (const float*)d_in[6];
    float* out = (float*)d_out;

    // workspace layout
    char* ws = (char*)d_ws;
    size_t off = 0;
    auto alloc = [&](size_t bytes) { void* p = ws + off; off += (bytes + 255) & ~(size_t)255; return p; };
    int*   cnt    = (int*)alloc(NN * 4);
    int*   cursor = (int*)alloc(NN * 4);
    int*   bsum   = (int*)alloc(NBLK * 4);
    float* dinv   = (float*)alloc(NN * 4);
    int2*  csr    = (int2*)alloc((size_t)NE * 8);
    float* h      = (float*)alloc((size_t)NN * HID * 4);
    float* bufA   = (float*)alloc((size_t)NN * HID * 4);
    float* bufB   = (float*)alloc((size_t)NN * HID * 4);
    float* bufC   = (float*)alloc((size_t)NN * HID * 4);
    float* accb   = (float*)alloc((size_t)NN * HID * 4);

    const int BN  = (NN + 255) / 256;
    const int BE  = (NE + 255) / 256;
    const int BNH = (NN * HID + 255) / 256;
    const int BP  = (NN + 3) / 4;            // 4 nodes (waves) per 256-block

    // --- CSR build ---
    k_zero<<<BN, 256, 0, stream>>>(cnt);
    k_hist<<<BE, 256, 0, stream>>>(ei, cnt);
    k_dinv<<<BN, 256, 0, stream>>>(cnt, dinv);
    k_scan1<<<NBLK, SCAN_BLK, 0, stream>>>(cnt, cursor, bsum);
    k_scan2<<<1, 64, 0, stream>>>(bsum);
    k_scan3<<<NBLK, SCAN_BLK, 0, stream>>>(cursor, bsum);
    k_scatter<<<BE, 256, 0, stream>>>(ei, dinv, cursor, csr);
    // cursor[i] is now end-offset of node i

    // --- h = relu(x @ W1 + b1) ---
    k_gemm1<<<(NN + 7) / 8, 512, 0, stream>>>(x, W1, b1, h);

    // rotation: gen k lives in rot[k & 3]; gen0 = h
    float* rot[4] = {h, bufA, bufB, bufC};

    for (int l = 0; l < 2; ++l) {
        int cbase = l * (KORD + 1);
        // k = 1: t1 = P h; acc = c0*h + c1*t1
        k_prop<<<BP, 256, 0, stream>>>(cursor, csr, rot[0], rot[0], dinv,
                                       rot[1], accb, 1.0f, 0.0f, 0.0f,
                                       coeffs, cbase, 1, 1);
        for (int k = 2; k <= KORD; ++k) {
            float* dst = rot[k & 3];
            const float* s1 = rot[(k - 1) & 3];
            const float* s0 = rot[(k - 2) & 3];
            double n = k - 1, a = 0.5, b = 0.5;
            double An = (2*n + a + b + 1) * (2*n + a + b + 2) / (2 * (n + 1) * (n + a + b + 1));
            double Bn = (a*a - b*b) * (2*n + a + b + 1) / (2 * (n + 1) * (n + a + b + 1) * (2*n + a + b));
            double Cn = (n + a) * (n + b) * (2*n + a + b + 2) / ((n + 1) * (n + a + b + 1) * (2*n + a + b));
            k_prop<<<BP, 256, 0, stream>>>(cursor, csr, s1, s0, dinv,
                                           dst, accb, (float)An, (float)Bn, (float)Cn,
                                           coeffs, cbase, k, 0);
        }
        k_relu<<<BNH, 256, 0, stream>>>(h, accb);
    }

    // out = h @ W2 + b2
    k_gemm2<<<(NN * 32 + 255) / 256, 256, 0, stream>>>(h, W2, b2, out);
}

// Round 3
// 1917.176 us; speedup vs baseline: 4.2255x; 1.1505x over previous
//
#include <hip/hip_runtime.h>

#define NN 100000
#define NE 1600000
#define KORD 10
#define HID 64
#define SCAN_BLK 1024
#define NBLK ((NN + SCAN_BLK - 1) / SCAN_BLK)   // 98

// ---------------- CSR build ----------------
__global__ __launch_bounds__(256) void k_zero(int* __restrict__ cnt) {
    int i = blockIdx.x * 256 + threadIdx.x;
    if (i < NN) cnt[i] = 0;
}

__global__ __launch_bounds__(256) void k_hist(const int* __restrict__ ei,
                                              int* __restrict__ cnt) {
    int e = blockIdx.x * 256 + threadIdx.x;
    if (e < NE) atomicAdd(&cnt[ei[NE + e]], 1);
}

__global__ __launch_bounds__(256) void k_dinv(const int* __restrict__ cnt,
                                              float* __restrict__ dinv) {
    int i = blockIdx.x * 256 + threadIdx.x;
    if (i < NN) dinv[i] = rsqrtf((float)(cnt[i] + 1));   // +1 self-loop
}

__global__ __launch_bounds__(SCAN_BLK) void k_scan1(const int* __restrict__ cnt,
                                                    int* __restrict__ cursor,
                                                    int* __restrict__ bsum) {
    __shared__ int tmp[SCAN_BLK];
    int t = threadIdx.x;
    int g = blockIdx.x * SCAN_BLK + t;
    int v = (g < NN) ? cnt[g] : 0;
    tmp[t] = v;
    __syncthreads();
    int x = v;
    for (int off = 1; off < SCAN_BLK; off <<= 1) {
        int y = (t >= off) ? tmp[t - off] : 0;
        __syncthreads();
        x += y;
        tmp[t] = x;
        __syncthreads();
    }
    if (g < NN) cursor[g] = x - v;
    if (t == SCAN_BLK - 1) bsum[blockIdx.x] = x;
}

__global__ void k_scan2(int* __restrict__ bsum) {
    if (threadIdx.x == 0) {
        int s = 0;
        for (int i = 0; i < NBLK; ++i) { int t = bsum[i]; bsum[i] = s; s += t; }
    }
}

__global__ __launch_bounds__(SCAN_BLK) void k_scan3(int* __restrict__ cursor,
                                                    const int* __restrict__ bsum) {
    int g = blockIdx.x * SCAN_BLK + threadIdx.x;
    if (g < NN) cursor[g] += bsum[blockIdx.x];
}

__global__ __launch_bounds__(256) void k_scatter(const int* __restrict__ ei,
                                                 const float* __restrict__ dinv,
                                                 int* __restrict__ cursor,
                                                 int2* __restrict__ csr) {
    int e = blockIdx.x * 256 + threadIdx.x;
    if (e >= NE) return;
    int r = ei[e], c = ei[NE + e];
    float wv = dinv[r] * dinv[c];
    int pos = atomicAdd(&cursor[c], 1);
    csr[pos] = make_int2(r, __float_as_int(wv));
}

// ---------- GEMM1: h = relu(x @ W1 + b1), register-blocked 64x64 tile ----------
// 256 threads: thread (tr = t>>4, tc = t&15) computes rows tr*4..+3, cols tc*4..+3.
#define G1_PAD 68   // row stride in floats (64 + 4), 16B aligned, breaks bank stride
__global__ __launch_bounds__(256) void k_gemm1(const float* __restrict__ x,
                                               const float* __restrict__ W1,
                                               const float* __restrict__ b1,
                                               float* __restrict__ h) {
    __shared__ float As[64 * G1_PAD];
    __shared__ float Bs[64 * G1_PAD];
    int t = threadIdx.x;
    int tr = t >> 4, tc = t & 15;
    int row0 = blockIdx.x * 64;

    float4 acc[4];
#pragma unroll
    for (int r = 0; r < 4; ++r) acc[r] = make_float4(0.f, 0.f, 0.f, 0.f);

    for (int kk = 0; kk < 256; kk += 64) {
        // stage A (x tile 64x64) and B (W1 tile 64x64)
#pragma unroll
        for (int i = 0; i < 4; ++i) {
            int idx = t + i * 256;            // 0..1023 float4 slots
            int r = idx >> 4, c4 = idx & 15;
            int grow = row0 + r;
            float4 av = (grow < NN) ? *(const float4*)&x[(size_t)grow * 256 + kk + c4 * 4]
                                    : make_float4(0.f, 0.f, 0.f, 0.f);
            *(float4*)&As[r * G1_PAD + c4 * 4] = av;
            float4 bv = *(const float4*)&W1[(size_t)(kk + r) * 64 + c4 * 4];
            *(float4*)&Bs[r * G1_PAD + c4 * 4] = bv;
        }
        __syncthreads();

#pragma unroll
        for (int k4 = 0; k4 < 16; ++k4) {
            float4 a[4], b[4];
#pragma unroll
            for (int r = 0; r < 4; ++r)
                a[r] = *(const float4*)&As[(tr * 4 + r) * G1_PAD + k4 * 4];
#pragma unroll
            for (int kk2 = 0; kk2 < 4; ++kk2)
                b[kk2] = *(const float4*)&Bs[(k4 * 4 + kk2) * G1_PAD + tc * 4];
#pragma unroll
            for (int r = 0; r < 4; ++r) {
                acc[r].x += a[r].x * b[0].x + a[r].y * b[1].x + a[r].z * b[2].x + a[r].w * b[3].x;
                acc[r].y += a[r].x * b[0].y + a[r].y * b[1].y + a[r].z * b[2].y + a[r].w * b[3].y;
                acc[r].z += a[r].x * b[0].z + a[r].y * b[1].z + a[r].z * b[2].z + a[r].w * b[3].z;
                acc[r].w += a[r].x * b[0].w + a[r].y * b[1].w + a[r].z * b[2].w + a[r].w * b[3].w;
            }
        }
        __syncthreads();
    }

    float4 bias = *(const float4*)&b1[tc * 4];
#pragma unroll
    for (int r = 0; r < 4; ++r) {
        int grow = row0 + tr * 4 + r;
        if (grow >= NN) continue;
        float4 v;
        v.x = fmaxf(acc[r].x + bias.x, 0.f);
        v.y = fmaxf(acc[r].y + bias.y, 0.f);
        v.z = fmaxf(acc[r].z + bias.z, 0.f);
        v.w = fmaxf(acc[r].w + bias.w, 0.f);
        *(float4*)&h[(size_t)grow * 64 + tc * 4] = v;
    }
}

// ---------- fused propagation + Jacobi combine, 4-edge vectorized ----------
// One wave per node. lane: sub = lane>>4 (edge slot in group of 4), ch4 = lane&15
// (float4 chunk of channels). Gathers are dwordx4; butterfly over sub folds partials.
__global__ __launch_bounds__(256) void k_prop(const int* __restrict__ cursor,   // end offsets
                                              const int2* __restrict__ csr,
                                              const float* __restrict__ src,
                                              const float* __restrict__ t0,
                                              const float* __restrict__ dinv,
                                              float* __restrict__ dst,
                                              float* __restrict__ acc,
                                              float* __restrict__ hout,
                                              float An, float Bn, float Cn,
                                              const float* __restrict__ coeffs,
                                              int cbase, int kidx, int init, int finalize) {
    int node = blockIdx.x * 4 + (threadIdx.x >> 6);
    int lane = threadIdx.x & 63;
    if (node >= NN) return;

    int beg = (node == 0) ? 0 : cursor[node - 1];
    int end = cursor[node];

    int sub = lane >> 4;
    int ch4 = (lane & 15) * 4;

    float4 p = make_float4(0.f, 0.f, 0.f, 0.f);
    const int2 ez = make_int2(0, 0);

    for (int j = beg; j < end; j += 8) {
        int j0 = j + sub, j1 = j + 4 + sub;
        int2 e0 = (j0 < end) ? csr[j0] : ez;
        int2 e1 = (j1 < end) ? csr[j1] : ez;
        float w0 = __int_as_float(e0.y);
        float w1 = __int_as_float(e1.y);
        float4 g0 = *(const float4*)&src[(size_t)e0.x * HID + ch4];
        float4 g1 = *(const float4*)&src[(size_t)e1.x * HID + ch4];
        p.x += w0 * g0.x; p.y += w0 * g0.y; p.z += w0 * g0.z; p.w += w0 * g0.w;
        p.x += w1 * g1.x; p.y += w1 * g1.y; p.z += w1 * g1.z; p.w += w1 * g1.w;
    }

    // fold the 4 sub-groups (lanes l, l^16, l^32 share ch4)
    p.x += __shfl_xor(p.x, 16); p.y += __shfl_xor(p.y, 16);
    p.z += __shfl_xor(p.z, 16); p.w += __shfl_xor(p.w, 16);
    p.x += __shfl_xor(p.x, 32); p.y += __shfl_xor(p.y, 32);
    p.z += __shfl_xor(p.z, 32); p.w += __shfl_xor(p.w, 32);

    if (sub == 0) {
        size_t idx = (size_t)node * HID + ch4;
        float dv = dinv[node];
        float dv2 = dv * dv;
        float4 s = *(const float4*)&src[idx];
        float4 t0v = *(const float4*)&t0[idx];
        float4 v;
        v.x = An * (p.x + dv2 * s.x) + Bn * s.x - Cn * t0v.x;
        v.y = An * (p.y + dv2 * s.y) + Bn * s.y - Cn * t0v.y;
        v.z = An * (p.z + dv2 * s.z) + Bn * s.z - Cn * t0v.z;
        v.w = An * (p.w + dv2 * s.w) + Bn * s.w - Cn * t0v.w;
        if (!finalize) *(float4*)&dst[idx] = v;

        float ck = coeffs[cbase + kidx];
        float4 a;
        if (init) {
            float c0 = coeffs[cbase];
            a = make_float4(c0 * s.x, c0 * s.y, c0 * s.z, c0 * s.w);
        } else {
            a = *(const float4*)&acc[idx];
        }
        a.x += ck * v.x; a.y += ck * v.y; a.z += ck * v.z; a.w += ck * v.w;
        if (finalize) {
            float4 r;
            r.x = fmaxf(a.x, 0.f); r.y = fmaxf(a.y, 0.f);
            r.z = fmaxf(a.z, 0.f); r.w = fmaxf(a.w, 0.f);
            *(float4*)&hout[idx] = r;
        } else {
            *(float4*)&acc[idx] = a;
        }
    }
}

// ---------- GEMM2: out = h @ W2 + b2 ----------
// thread: row = gid>>3, cols = (t&7)*4; float4 everywhere.
__global__ __launch_bounds__(256) void k_gemm2(const float* __restrict__ h,
                                               const float* __restrict__ W2,
                                               const float* __restrict__ b2,
                                               float* __restrict__ out) {
    __shared__ float W2s[64 * 32];
    __shared__ float b2s[32];
    int t = threadIdx.x;
    for (int i = t * 4; i < 64 * 32; i += 256 * 4)
        *(float4*)&W2s[i] = *(const float4*)&W2[i];
    if (t < 32) b2s[t] = b2[t];
    __syncthreads();

    int gid = blockIdx.x * 256 + t;
    int row = gid >> 3;
    int c4 = (t & 7) * 4;
    if (row >= NN) return;
    const float* hr = h + (size_t)row * 64;
    float4 acc = *(const float4*)&b2s[c4];
#pragma unroll
    for (int k4 = 0; k4 < 16; ++k4) {
        float4 a = *(const float4*)&hr[k4 * 4];
        float4 w0 = *(const float4*)&W2s[(k4 * 4 + 0) * 32 + c4];
        float4 w1 = *(const float4*)&W2s[(k4 * 4 + 1) * 32 + c4];
        float4 w2 = *(const float4*)&W2s[(k4 * 4 + 2) * 32 + c4];
        float4 w3 = *(const float4*)&W2s[(k4 * 4 + 3) * 32 + c4];
        acc.x += a.x * w0.x + a.y * w1.x + a.z * w2.x + a.w * w3.x;
        acc.y += a.x * w0.y + a.y * w1.y + a.z * w2.y + a.w * w3.y;
        acc.z += a.x * w0.z + a.y * w1.z + a.z * w2.z + a.w * w3.z;
        acc.w += a.x * w0.w + a.y * w1.w + a.z * w2.w + a.w * w3.w;
    }
    *(float4*)&out[(size_t)row * 32 + c4] = acc;
}

extern "C" void kernel_launch(void* const* d_in, const int* in_sizes, int n_in,
                              void* d_out, int out_size, void* d_ws, size_t ws_size,
                              hipStream_t stream) {
    const float* x      = (const float*)d_in[0];
    const int*   ei     = (const int*)d_in[1];
    const float* W1     = (const float*)d_in[2];
    const float* b1     = (const float*)d_in[3];
    const float* coeffs = (const float*)d_in[4];
    const float* W2     = (const float*)d_in[5];
    const float* b2     = (const float*)d_in[6];
    float* out = (float*)d_out;

    char* ws = (char*)d_ws;
    size_t off = 0;
    auto alloc = [&](size_t bytes) { void* p = ws + off; off += (bytes + 255) & ~(size_t)255; return p; };
    int*   cnt    = (int*)alloc(NN * 4);
    int*   cursor = (int*)alloc(NN * 4);
    int*   bsum   = (int*)alloc(NBLK * 4);
    float* dinv   = (float*)alloc(NN * 4);
    int2*  csr    = (int2*)alloc((size_t)NE * 8);
    float* h      = (float*)alloc((size_t)NN * HID * 4);
    float* bufA   = (float*)alloc((size_t)NN * HID * 4);
    float* bufB   = (float*)alloc((size_t)NN * HID * 4);
    float* bufC   = (float*)alloc((size_t)NN * HID * 4);
    float* accb   = (float*)alloc((size_t)NN * HID * 4);

    const int BN = (NN + 255) / 256;
    const int BE = (NE + 255) / 256;
    const int BP = (NN + 3) / 4;

    // --- CSR build ---
    k_zero<<<BN, 256, 0, stream>>>(cnt);
    k_hist<<<BE, 256, 0, stream>>>(ei, cnt);
    k_dinv<<<BN, 256, 0, stream>>>(cnt, dinv);
    k_scan1<<<NBLK, SCAN_BLK, 0, stream>>>(cnt, cursor, bsum);
    k_scan2<<<1, 64, 0, stream>>>(bsum);
    k_scan3<<<NBLK, SCAN_BLK, 0, stream>>>(cursor, bsum);
    k_scatter<<<BE, 256, 0, stream>>>(ei, dinv, cursor, csr);

    // --- h = relu(x @ W1 + b1) ---
    k_gemm1<<<(NN + 63) / 64, 256, 0, stream>>>(x, W1, b1, h);

    float* rot[4] = {h, bufA, bufB, bufC};

    for (int l = 0; l < 2; ++l) {
        int cbase = l * (KORD + 1);
        // k = 1
        k_prop<<<BP, 256, 0, stream>>>(cursor, csr, rot[0], rot[0], dinv,
                                       rot[1], accb, h, 1.0f, 0.0f, 0.0f,
                                       coeffs, cbase, 1, 1, 0);
        for (int k = 2; k <= KORD; ++k) {
            float* dst = rot[k & 3];
            const float* s1 = rot[(k - 1) & 3];
            const float* s0 = rot[(k - 2) & 3];
            double n = k - 1, a = 0.5, b = 0.5;
            double An = (2*n + a + b + 1) * (2*n + a + b + 2) / (2 * (n + 1) * (n + a + b + 1));
            double Bn = (a*a - b*b) * (2*n + a + b + 1) / (2 * (n + 1) * (n + a + b + 1) * (2*n + a + b));
            double Cn = (n + a) * (n + b) * (2*n + a + b + 2) / ((n + 1) * (n + a + b + 1) * (2*n + a + b));
            k_prop<<<BP, 256, 0, stream>>>(cursor, csr, s1, s0, dinv,
                                           dst, accb, h, (float)An, (float)Bn, (float)Cn,
                                           coeffs, cbase, k, 0, (k == KORD) ? 1 : 0);
        }
        // finalize=1 wrote h = relu(acc) in the k=KORD epilogue
    }

    // out = h @ W2 + b2
    k_gemm2<<<(NN * 8 + 255) / 256, 256, 0, stream>>>(h, W2, b2, out);
}

// Round 4
// 1549.030 us; speedup vs baseline: 5.2298x; 1.2377x over previous
//
#include <hip/hip_runtime.h>
#include <hip/hip_fp16.h>

#define NN 100000
#define NE 1600000
#define KORD 10
#define HID 64
#define SCAN_BLK 1024
#define NBLK ((NN + SCAN_BLK - 1) / SCAN_BLK)   // 98

__device__ __forceinline__ float2 up2(unsigned u) {
    __half2 hh = *(__half2*)&u;
    return __half22float2(hh);
}
__device__ __forceinline__ unsigned pk2(float a, float b) {
    __half2 hh = __floats2half2_rn(a, b);
    return *(unsigned*)&hh;
}

// ---------------- CSR build ----------------
__global__ __launch_bounds__(256) void k_zero(int* __restrict__ cnt) {
    int i = blockIdx.x * 256 + threadIdx.x;
    if (i < NN) cnt[i] = 0;
}

__global__ __launch_bounds__(256) void k_hist(const int* __restrict__ ei,
                                              int* __restrict__ cnt) {
    int e = blockIdx.x * 256 + threadIdx.x;
    if (e < NE) atomicAdd(&cnt[ei[NE + e]], 1);
}

__global__ __launch_bounds__(256) void k_dinv(const int* __restrict__ cnt,
                                              float* __restrict__ dinv) {
    int i = blockIdx.x * 256 + threadIdx.x;
    if (i < NN) dinv[i] = rsqrtf((float)(cnt[i] + 1));   // +1 self-loop
}

__global__ __launch_bounds__(SCAN_BLK) void k_scan1(const int* __restrict__ cnt,
                                                    int* __restrict__ cursor,
                                                    int* __restrict__ bsum) {
    __shared__ int tmp[SCAN_BLK];
    int t = threadIdx.x;
    int g = blockIdx.x * SCAN_BLK + t;
    int v = (g < NN) ? cnt[g] : 0;
    tmp[t] = v;
    __syncthreads();
    int x = v;
    for (int off = 1; off < SCAN_BLK; off <<= 1) {
        int y = (t >= off) ? tmp[t - off] : 0;
        __syncthreads();
        x += y;
        tmp[t] = x;
        __syncthreads();
    }
    if (g < NN) cursor[g] = x - v;
    if (t == SCAN_BLK - 1) bsum[blockIdx.x] = x;
}

__global__ void k_scan2(int* __restrict__ bsum) {
    if (threadIdx.x == 0) {
        int s = 0;
        for (int i = 0; i < NBLK; ++i) { int t = bsum[i]; bsum[i] = s; s += t; }
    }
}

__global__ __launch_bounds__(SCAN_BLK) void k_scan3(int* __restrict__ cursor,
                                                    const int* __restrict__ bsum) {
    int g = blockIdx.x * SCAN_BLK + threadIdx.x;
    if (g < NN) cursor[g] += bsum[blockIdx.x];
}

__global__ __launch_bounds__(256) void k_scatter(const int* __restrict__ ei,
                                                 const float* __restrict__ dinv,
                                                 int* __restrict__ cursor,
                                                 int2* __restrict__ csr) {
    int e = blockIdx.x * 256 + threadIdx.x;
    if (e >= NE) return;
    int r = ei[e], c = ei[NE + e];
    float wv = dinv[r] * dinv[c];
    int pos = atomicAdd(&cursor[c], 1);
    csr[pos] = make_int2(r, __float_as_int(wv));
}

// ---------- GEMM1: h = relu(x @ W1 + b1), register-blocked 64x64 tile, fp16 out ----------
#define G1_PAD 68
__global__ __launch_bounds__(256) void k_gemm1(const float* __restrict__ x,
                                               const float* __restrict__ W1,
                                               const float* __restrict__ b1,
                                               __half* __restrict__ h) {
    __shared__ float As[64 * G1_PAD];
    __shared__ float Bs[64 * G1_PAD];
    int t = threadIdx.x;
    int tr = t >> 4, tc = t & 15;
    int row0 = blockIdx.x * 64;

    float4 acc[4];
#pragma unroll
    for (int r = 0; r < 4; ++r) acc[r] = make_float4(0.f, 0.f, 0.f, 0.f);

    for (int kk = 0; kk < 256; kk += 64) {
#pragma unroll
        for (int i = 0; i < 4; ++i) {
            int idx = t + i * 256;
            int r = idx >> 4, c4 = idx & 15;
            int grow = row0 + r;
            float4 av = (grow < NN) ? *(const float4*)&x[(size_t)grow * 256 + kk + c4 * 4]
                                    : make_float4(0.f, 0.f, 0.f, 0.f);
            *(float4*)&As[r * G1_PAD + c4 * 4] = av;
            float4 bv = *(const float4*)&W1[(size_t)(kk + r) * 64 + c4 * 4];
            *(float4*)&Bs[r * G1_PAD + c4 * 4] = bv;
        }
        __syncthreads();

#pragma unroll
        for (int k4 = 0; k4 < 16; ++k4) {
            float4 a[4], b[4];
#pragma unroll
            for (int r = 0; r < 4; ++r)
                a[r] = *(const float4*)&As[(tr * 4 + r) * G1_PAD + k4 * 4];
#pragma unroll
            for (int kk2 = 0; kk2 < 4; ++kk2)
                b[kk2] = *(const float4*)&Bs[(k4 * 4 + kk2) * G1_PAD + tc * 4];
#pragma unroll
            for (int r = 0; r < 4; ++r) {
                acc[r].x += a[r].x * b[0].x + a[r].y * b[1].x + a[r].z * b[2].x + a[r].w * b[3].x;
                acc[r].y += a[r].x * b[0].y + a[r].y * b[1].y + a[r].z * b[2].y + a[r].w * b[3].y;
                acc[r].z += a[r].x * b[0].z + a[r].y * b[1].z + a[r].z * b[2].z + a[r].w * b[3].z;
                acc[r].w += a[r].x * b[0].w + a[r].y * b[1].w + a[r].z * b[2].w + a[r].w * b[3].w;
            }
        }
        __syncthreads();
    }

    float4 bias = *(const float4*)&b1[tc * 4];
#pragma unroll
    for (int r = 0; r < 4; ++r) {
        int grow = row0 + tr * 4 + r;
        if (grow >= NN) continue;
        float vx = fmaxf(acc[r].x + bias.x, 0.f);
        float vy = fmaxf(acc[r].y + bias.y, 0.f);
        float vz = fmaxf(acc[r].z + bias.z, 0.f);
        float vw = fmaxf(acc[r].w + bias.w, 0.f);
        uint2 st;
        st.x = pk2(vx, vy);
        st.y = pk2(vz, vw);
        *(uint2*)&h[(size_t)grow * 64 + tc * 4] = st;
    }
}

// ---------- fused propagation + Jacobi combine, fp16 features ----------
// One wave per node. sub = lane>>3 (edge slot in group of 8), ch8 = (lane&7)*8
// (8 halves = 16B per lane). One dwordx4 gathers 8 edges per wave-instruction.
__global__ __launch_bounds__(256) void k_prop(const int* __restrict__ cursor,   // end offsets
                                              const int2* __restrict__ csr,
                                              const __half* __restrict__ src,
                                              const __half* __restrict__ t0,
                                              const float* __restrict__ dinv,
                                              __half* __restrict__ dst,
                                              float* __restrict__ acc,
                                              __half* __restrict__ hout,
                                              float An, float Bn, float Cn,
                                              const float* __restrict__ coeffs,
                                              int cbase, int kidx, int init, int finalize) {
    int node = blockIdx.x * 4 + (threadIdx.x >> 6);
    int lane = threadIdx.x & 63;
    if (node >= NN) return;

    int beg = (node == 0) ? 0 : cursor[node - 1];
    int end = cursor[node];

    int sub = lane >> 3;
    int ch8 = (lane & 7) * 8;

    float p[8];
#pragma unroll
    for (int i = 0; i < 8; ++i) p[i] = 0.f;

    for (int j = beg; j < end; j += 8) {
        int jj = j + sub;
        int2 e = (jj < end) ? csr[jj] : make_int2(0, 0);
        float w = __int_as_float(e.y);
        uint4 raw = *(const uint4*)&src[(size_t)e.x * HID + ch8];
        float2 f0 = up2(raw.x), f1 = up2(raw.y), f2 = up2(raw.z), f3 = up2(raw.w);
        p[0] += w * f0.x; p[1] += w * f0.y;
        p[2] += w * f1.x; p[3] += w * f1.y;
        p[4] += w * f2.x; p[5] += w * f2.y;
        p[6] += w * f3.x; p[7] += w * f3.y;
    }

    // fold 8 sub-groups: lanes l, l^8, l^16, l^32 share ch8
#pragma unroll
    for (int m = 8; m <= 32; m <<= 1) {
#pragma unroll
        for (int i = 0; i < 8; ++i) p[i] += __shfl_xor(p[i], m);
    }

    if (sub != 0) return;
    // lanes 0..7 active; lane holds channels ch8..ch8+7
    size_t idx = (size_t)node * HID + ch8;
    float dv = dinv[node];
    float dv2 = dv * dv;

    uint4 sr = *(const uint4*)&src[idx];
    float2 s01 = up2(sr.x), s23 = up2(sr.y), s45 = up2(sr.z), s67 = up2(sr.w);
    float sv[8] = {s01.x, s01.y, s23.x, s23.y, s45.x, s45.y, s67.x, s67.y};

    uint4 tr = *(const uint4*)&t0[idx];
    float2 t01 = up2(tr.x), t23 = up2(tr.y), t45 = up2(tr.z), t67 = up2(tr.w);
    float tv[8] = {t01.x, t01.y, t23.x, t23.y, t45.x, t45.y, t67.x, t67.y};

    float v[8];
#pragma unroll
    for (int i = 0; i < 8; ++i)
        v[i] = An * (p[i] + dv2 * sv[i]) + Bn * sv[i] - Cn * tv[i];

    if (!finalize) {
        uint4 o;
        o.x = pk2(v[0], v[1]); o.y = pk2(v[2], v[3]);
        o.z = pk2(v[4], v[5]); o.w = pk2(v[6], v[7]);
        *(uint4*)&dst[idx] = o;
    }

    float ck = coeffs[cbase + kidx];
    float av[8];
    if (init) {
        float c0 = coeffs[cbase];
#pragma unroll
        for (int i = 0; i < 8; ++i) av[i] = c0 * sv[i];
    } else {
        float4 a0 = *(const float4*)&acc[idx];
        float4 a1 = *(const float4*)&acc[idx + 4];
        av[0] = a0.x; av[1] = a0.y; av[2] = a0.z; av[3] = a0.w;
        av[4] = a1.x; av[5] = a1.y; av[6] = a1.z; av[7] = a1.w;
    }
#pragma unroll
    for (int i = 0; i < 8; ++i) av[i] += ck * v[i];

    if (finalize) {
        uint4 o;
        o.x = pk2(fmaxf(av[0], 0.f), fmaxf(av[1], 0.f));
        o.y = pk2(fmaxf(av[2], 0.f), fmaxf(av[3], 0.f));
        o.z = pk2(fmaxf(av[4], 0.f), fmaxf(av[5], 0.f));
        o.w = pk2(fmaxf(av[6], 0.f), fmaxf(av[7], 0.f));
        *(uint4*)&hout[idx] = o;
    } else {
        *(float4*)&acc[idx]     = make_float4(av[0], av[1], av[2], av[3]);
        *(float4*)&acc[idx + 4] = make_float4(av[4], av[5], av[6], av[7]);
    }
}

// ---------- GEMM2: out = h16 @ W2 + b2 ----------
__global__ __launch_bounds__(256) void k_gemm2(const __half* __restrict__ h,
                                               const float* __restrict__ W2,
                                               const float* __restrict__ b2,
                                               float* __restrict__ out) {
    __shared__ float W2s[64 * 32];
    __shared__ float b2s[32];
    int t = threadIdx.x;
    for (int i = t * 4; i < 64 * 32; i += 256 * 4)
        *(float4*)&W2s[i] = *(const float4*)&W2[i];
    if (t < 32) b2s[t] = b2[t];
    __syncthreads();

    int gid = blockIdx.x * 256 + t;
    int row = gid >> 3;
    int c4 = (t & 7) * 4;
    if (row >= NN) return;
    const __half* hr = h + (size_t)row * 64;
    float4 acc = *(const float4*)&b2s[c4];
#pragma unroll
    for (int k8 = 0; k8 < 8; ++k8) {
        uint4 raw = *(const uint4*)&hr[k8 * 8];
        float2 a01 = up2(raw.x), a23 = up2(raw.y), a45 = up2(raw.z), a67 = up2(raw.w);
        float a[8] = {a01.x, a01.y, a23.x, a23.y, a45.x, a45.y, a67.x, a67.y};
#pragma unroll
        for (int j = 0; j < 8; ++j) {
            float4 w = *(const float4*)&W2s[(k8 * 8 + j) * 32 + c4];
            acc.x += a[j] * w.x;
            acc.y += a[j] * w.y;
            acc.z += a[j] * w.z;
            acc.w += a[j] * w.w;
        }
    }
    *(float4*)&out[(size_t)row * 32 + c4] = acc;
}

extern "C" void kernel_launch(void* const* d_in, const int* in_sizes, int n_in,
                              void* d_out, int out_size, void* d_ws, size_t ws_size,
                              hipStream_t stream) {
    const float* x      = (const float*)d_in[0];
    const int*   ei     = (const int*)d_in[1];
    const float* W1     = (const float*)d_in[2];
    const float* b1     = (const float*)d_in[3];
    const float* coeffs = (const float*)d_in[4];
    const float* W2     = (const float*)d_in[5];
    const float* b2     = (const float*)d_in[6];
    float* out = (float*)d_out;

    char* ws = (char*)d_ws;
    size_t off = 0;
    auto alloc = [&](size_t bytes) { void* p = ws + off; off += (bytes + 255) & ~(size_t)255; return p; };
    int*    cnt    = (int*)alloc(NN * 4);
    int*    cursor = (int*)alloc(NN * 4);
    int*    bsum   = (int*)alloc(NBLK * 4);
    float*  dinv   = (float*)alloc(NN * 4);
    int2*   csr    = (int2*)alloc((size_t)NE * 8);
    __half* h16    = (__half*)alloc((size_t)NN * HID * 2);
    __half* bufA   = (__half*)alloc((size_t)NN * HID * 2);
    __half* bufB   = (__half*)alloc((size_t)NN * HID * 2);
    __half* bufC   = (__half*)alloc((size_t)NN * HID * 2);
    float*  accb   = (float*)alloc((size_t)NN * HID * 4);

    const int BN = (NN + 255) / 256;
    const int BE = (NE + 255) / 256;
    const int BP = (NN + 3) / 4;

    // --- CSR build ---
    k_zero<<<BN, 256, 0, stream>>>(cnt);
    k_hist<<<BE, 256, 0, stream>>>(ei, cnt);
    k_dinv<<<BN, 256, 0, stream>>>(cnt, dinv);
    k_scan1<<<NBLK, SCAN_BLK, 0, stream>>>(cnt, cursor, bsum);
    k_scan2<<<1, 64, 0, stream>>>(bsum);
    k_scan3<<<NBLK, SCAN_BLK, 0, stream>>>(cursor, bsum);
    k_scatter<<<BE, 256, 0, stream>>>(ei, dinv, cursor, csr);

    // --- h = relu(x @ W1 + b1) ---
    k_gemm1<<<(NN + 63) / 64, 256, 0, stream>>>(x, W1, b1, h16);

    __half* rot[4] = {h16, bufA, bufB, bufC};

    for (int l = 0; l < 2; ++l) {
        int cbase = l * (KORD + 1);
        k_prop<<<BP, 256, 0, stream>>>(cursor, csr, rot[0], rot[0], dinv,
                                       rot[1], accb, h16, 1.0f, 0.0f, 0.0f,
                                       coeffs, cbase, 1, 1, 0);
        for (int k = 2; k <= KORD; ++k) {
            __half* dst = rot[k & 3];
            const __half* s1 = rot[(k - 1) & 3];
            const __half* s0 = rot[(k - 2) & 3];
            double n = k - 1, a = 0.5, b = 0.5;
            double An = (2*n + a + b + 1) * (2*n + a + b + 2) / (2 * (n + 1) * (n + a + b + 1));
            double Bn = (a*a - b*b) * (2*n + a + b + 1) / (2 * (n + 1) * (n + a + b + 1) * (2*n + a + b));
            double Cn = (n + a) * (n + b) * (2*n + a + b + 2) / ((n + 1) * (n + a + b + 1) * (2*n + a + b));
            k_prop<<<BP, 256, 0, stream>>>(cursor, csr, s1, s0, dinv,
                                           dst, accb, h16, (float)An, (float)Bn, (float)Cn,
                                           coeffs, cbase, k, 0, (k == KORD) ? 1 : 0);
        }
    }

    // out = h @ W2 + b2
    k_gemm2<<<(NN * 8 + 255) / 256, 256, 0, stream>>>(h16, W2, b2, out);
}

// Round 5
// 1419.394 us; speedup vs baseline: 5.7074x; 1.0913x over previous
//
#include <hip/hip_runtime.h>
#include <hip/hip_fp16.h>

#define NN 100000
#define NE 1600000
#define KORD 10
#define HID 64
#define SCAN_BLK 1024
#define NBLK ((NN + SCAN_BLK - 1) / SCAN_BLK)   // 98

typedef _Float16 half8v __attribute__((ext_vector_type(8)));
typedef _Float16 half4v __attribute__((ext_vector_type(4)));
typedef float float4v __attribute__((ext_vector_type(4)));

__device__ __forceinline__ float2 up2(unsigned u) {
    __half2 hh = *(__half2*)&u;
    return __half22float2(hh);
}
__device__ __forceinline__ unsigned pk2(float a, float b) {
    __half2 hh = __floats2half2_rn(a, b);
    return *(unsigned*)&hh;
}

// ---------------- CSR build ----------------
__global__ __launch_bounds__(256) void k_zero(int* __restrict__ cnt) {
    int i = blockIdx.x * 256 + threadIdx.x;
    if (i < NN) cnt[i] = 0;
}

__global__ __launch_bounds__(256) void k_hist(const int* __restrict__ ei,
                                              int* __restrict__ cnt) {
    int e = blockIdx.x * 256 + threadIdx.x;
    if (e < NE) atomicAdd(&cnt[ei[NE + e]], 1);
}

__global__ __launch_bounds__(256) void k_dinv(const int* __restrict__ cnt,
                                              float* __restrict__ dinv) {
    int i = blockIdx.x * 256 + threadIdx.x;
    if (i < NN) dinv[i] = rsqrtf((float)(cnt[i] + 1));   // +1 self-loop
}

__global__ __launch_bounds__(SCAN_BLK) void k_scan1(const int* __restrict__ cnt,
                                                    int* __restrict__ cursor,
                                                    int* __restrict__ bsum) {
    __shared__ int tmp[SCAN_BLK];
    int t = threadIdx.x;
    int g = blockIdx.x * SCAN_BLK + t;
    int v = (g < NN) ? cnt[g] : 0;
    tmp[t] = v;
    __syncthreads();
    int x = v;
    for (int off = 1; off < SCAN_BLK; off <<= 1) {
        int y = (t >= off) ? tmp[t - off] : 0;
        __syncthreads();
        x += y;
        tmp[t] = x;
        __syncthreads();
    }
    if (g < NN) cursor[g] = x - v;
    if (t == SCAN_BLK - 1) bsum[blockIdx.x] = x;
}

__global__ void k_scan2(int* __restrict__ bsum) {
    if (threadIdx.x == 0) {
        int s = 0;
        for (int i = 0; i < NBLK; ++i) { int t = bsum[i]; bsum[i] = s; s += t; }
    }
}

__global__ __launch_bounds__(SCAN_BLK) void k_scan3(int* __restrict__ cursor,
                                                    const int* __restrict__ bsum) {
    int g = blockIdx.x * SCAN_BLK + threadIdx.x;
    if (g < NN) cursor[g] += bsum[blockIdx.x];
}

__global__ __launch_bounds__(256) void k_scatter(const int* __restrict__ ei,
                                                 const float* __restrict__ dinv,
                                                 int* __restrict__ cursor,
                                                 int2* __restrict__ csr) {
    int e = blockIdx.x * 256 + threadIdx.x;
    if (e >= NE) return;
    int r = ei[e], c = ei[NE + e];
    float wv = dinv[r] * dinv[c];
    int pos = atomicAdd(&cursor[c], 1);
    csr[pos] = make_int2(r, __float_as_int(wv));
}

// ---------- W1 transpose + fp16 cast: W1T[n][k] = W1[k][n] ----------
__global__ __launch_bounds__(256) void k_prepw1(const float* __restrict__ W1,
                                                _Float16* __restrict__ W1T) {
    int f = blockIdx.x * 256 + threadIdx.x;   // 0..16383
    int n = f >> 8, k = f & 255;
    W1T[f] = (_Float16)W1[k * 64 + n];
}

// ---------- GEMM1 via MFMA: h = relu(x @ W1 + b1) ----------
// Block: 256 thr = 4 waves, 64 rows. K=256 in 2 chunks of 128.
// A_lds: 64 rows x 136 f16 (128 + 8 pad); B_lds: 64 cols x 136 f16 (n-major).
#define G1K 128
#define G1S 136
__global__ __launch_bounds__(256) void k_gemm1(const float* __restrict__ x,
                                               const _Float16* __restrict__ W1T,
                                               const float* __restrict__ b1,
                                               __half* __restrict__ h) {
    __shared__ _Float16 A_lds[64 * G1S];
    __shared__ _Float16 B_lds[64 * G1S];
    int t = threadIdx.x;
    int wave = t >> 6, lane = t & 63;
    int quad = lane >> 4, m16 = lane & 15;
    int row0 = blockIdx.x * 64;

    float4v acc[4];
#pragma unroll
    for (int n4 = 0; n4 < 4; ++n4) acc[n4] = (float4v){0.f, 0.f, 0.f, 0.f};

    for (int c = 0; c < 2; ++c) {
        int k0 = c * G1K;
        // stage A: 64 x 128 f32 -> f16 (2048 float4 slots, 8 iters)
#pragma unroll
        for (int i = 0; i < 8; ++i) {
            int f = i * 256 + t;
            int r = f >> 5, c4 = f & 31;
            int grow = row0 + r;
            float4 v = (grow < NN) ? *(const float4*)&x[(size_t)grow * 256 + k0 + c4 * 4]
                                   : make_float4(0.f, 0.f, 0.f, 0.f);
            half4v hv = {(_Float16)v.x, (_Float16)v.y, (_Float16)v.z, (_Float16)v.w};
            *(half4v*)&A_lds[r * G1S + c4 * 4] = hv;
        }
        // stage B: W1T 64 x 128 f16 (1024 x 8-half slots, 4 iters)
#pragma unroll
        for (int i = 0; i < 4; ++i) {
            int f = i * 256 + t;
            int n = f >> 4, k8 = f & 15;
            *(half8v*)&B_lds[n * G1S + k8 * 8] =
                *(const half8v*)&W1T[n * 256 + k0 + k8 * 8];
        }
        __syncthreads();

#pragma unroll
        for (int s = 0; s < 4; ++s) {
            half8v af = *(const half8v*)&A_lds[(wave * 16 + m16) * G1S + s * 32 + quad * 8];
#pragma unroll
            for (int n4 = 0; n4 < 4; ++n4) {
                half8v bf = *(const half8v*)&B_lds[(n4 * 16 + m16) * G1S + s * 32 + quad * 8];
                acc[n4] = __builtin_amdgcn_mfma_f32_16x16x32_f16(af, bf, acc[n4], 0, 0, 0);
            }
        }
        __syncthreads();
    }

    // C/D: col = n4*16 + m16, row = quad*4 + r
    float bv[4];
#pragma unroll
    for (int n4 = 0; n4 < 4; ++n4) bv[n4] = b1[n4 * 16 + m16];
#pragma unroll
    for (int r = 0; r < 4; ++r) {
        int grow = row0 + wave * 16 + quad * 4 + r;
        if (grow >= NN) continue;
#pragma unroll
        for (int n4 = 0; n4 < 4; ++n4) {
            float v = fmaxf(acc[n4][r] + bv[n4], 0.f);
            h[(size_t)grow * 64 + n4 * 16 + m16] = __float2half(v);
        }
    }
}

// ---------- fused propagation + Jacobi combine, fp16 features + fp16 acc ----------
__global__ __launch_bounds__(256) void k_prop(const int* __restrict__ cursor,   // end offsets
                                              const int2* __restrict__ csr,
                                              const __half* __restrict__ src,
                                              const __half* __restrict__ t0,
                                              const float* __restrict__ dinv,
                                              __half* __restrict__ dst,
                                              __half* __restrict__ acc,
                                              __half* __restrict__ hout,
                                              float An, float Bn, float Cn,
                                              const float* __restrict__ coeffs,
                                              int cbase, int kidx, int init, int finalize) {
    int node = blockIdx.x * 4 + (threadIdx.x >> 6);
    int lane = threadIdx.x & 63;
    if (node >= NN) return;

    int beg = (node == 0) ? 0 : cursor[node - 1];
    int end = cursor[node];

    int sub = lane >> 3;
    int ch8 = (lane & 7) * 8;

    float p[8];
#pragma unroll
    for (int i = 0; i < 8; ++i) p[i] = 0.f;

    for (int j = beg; j < end; j += 8) {
        int jj = j + sub;
        int2 e = (jj < end) ? csr[jj] : make_int2(0, 0);
        float w = __int_as_float(e.y);
        uint4 raw = *(const uint4*)&src[(size_t)e.x * HID + ch8];
        float2 f0 = up2(raw.x), f1 = up2(raw.y), f2 = up2(raw.z), f3 = up2(raw.w);
        p[0] += w * f0.x; p[1] += w * f0.y;
        p[2] += w * f1.x; p[3] += w * f1.y;
        p[4] += w * f2.x; p[5] += w * f2.y;
        p[6] += w * f3.x; p[7] += w * f3.y;
    }

#pragma unroll
    for (int m = 8; m <= 32; m <<= 1) {
#pragma unroll
        for (int i = 0; i < 8; ++i) p[i] += __shfl_xor(p[i], m);
    }

    if (sub != 0) return;
    size_t idx = (size_t)node * HID + ch8;
    float dv = dinv[node];
    float dv2 = dv * dv;

    uint4 sr = *(const uint4*)&src[idx];
    float2 s01 = up2(sr.x), s23 = up2(sr.y), s45 = up2(sr.z), s67 = up2(sr.w);
    float sv[8] = {s01.x, s01.y, s23.x, s23.y, s45.x, s45.y, s67.x, s67.y};

    uint4 tr = *(const uint4*)&t0[idx];
    float2 t01 = up2(tr.x), t23 = up2(tr.y), t45 = up2(tr.z), t67 = up2(tr.w);
    float tv[8] = {t01.x, t01.y, t23.x, t23.y, t45.x, t45.y, t67.x, t67.y};

    float v[8];
#pragma unroll
    for (int i = 0; i < 8; ++i)
        v[i] = An * (p[i] + dv2 * sv[i]) + Bn * sv[i] - Cn * tv[i];

    if (!finalize) {
        uint4 o;
        o.x = pk2(v[0], v[1]); o.y = pk2(v[2], v[3]);
        o.z = pk2(v[4], v[5]); o.w = pk2(v[6], v[7]);
        *(uint4*)&dst[idx] = o;
    }

    float ck = coeffs[cbase + kidx];
    float av[8];
    if (init) {
        float c0 = coeffs[cbase];
#pragma unroll
        for (int i = 0; i < 8; ++i) av[i] = c0 * sv[i];
    } else {
        uint4 ar = *(const uint4*)&acc[idx];
        float2 a01 = up2(ar.x), a23 = up2(ar.y), a45 = up2(ar.z), a67 = up2(ar.w);
        av[0] = a01.x; av[1] = a01.y; av[2] = a23.x; av[3] = a23.y;
        av[4] = a45.x; av[5] = a45.y; av[6] = a67.x; av[7] = a67.y;
    }
#pragma unroll
    for (int i = 0; i < 8; ++i) av[i] += ck * v[i];

    uint4 o;
    if (finalize) {
        o.x = pk2(fmaxf(av[0], 0.f), fmaxf(av[1], 0.f));
        o.y = pk2(fmaxf(av[2], 0.f), fmaxf(av[3], 0.f));
        o.z = pk2(fmaxf(av[4], 0.f), fmaxf(av[5], 0.f));
        o.w = pk2(fmaxf(av[6], 0.f), fmaxf(av[7], 0.f));
        *(uint4*)&hout[idx] = o;
    } else {
        o.x = pk2(av[0], av[1]); o.y = pk2(av[2], av[3]);
        o.z = pk2(av[4], av[5]); o.w = pk2(av[6], av[7]);
        *(uint4*)&acc[idx] = o;
    }
}

// ---------- GEMM2: out = h16 @ W2 + b2 ----------
__global__ __launch_bounds__(256) void k_gemm2(const __half* __restrict__ h,
                                               const float* __restrict__ W2,
                                               const float* __restrict__ b2,
                                               float* __restrict__ out) {
    __shared__ float W2s[64 * 32];
    __shared__ float b2s[32];
    int t = threadIdx.x;
    for (int i = t * 4; i < 64 * 32; i += 256 * 4)
        *(float4*)&W2s[i] = *(const float4*)&W2[i];
    if (t < 32) b2s[t] = b2[t];
    __syncthreads();

    int gid = blockIdx.x * 256 + t;
    int row = gid >> 3;
    int c4 = (t & 7) * 4;
    if (row >= NN) return;
    const __half* hr = h + (size_t)row * 64;
    float4 acc = *(const float4*)&b2s[c4];
#pragma unroll
    for (int k8 = 0; k8 < 8; ++k8) {
        uint4 raw = *(const uint4*)&hr[k8 * 8];
        float2 a01 = up2(raw.x), a23 = up2(raw.y), a45 = up2(raw.z), a67 = up2(raw.w);
        float a[8] = {a01.x, a01.y, a23.x, a23.y, a45.x, a45.y, a67.x, a67.y};
#pragma unroll
        for (int j = 0; j < 8; ++j) {
            float4 w = *(const float4*)&W2s[(k8 * 8 + j) * 32 + c4];
            acc.x += a[j] * w.x;
            acc.y += a[j] * w.y;
            acc.z += a[j] * w.z;
            acc.w += a[j] * w.w;
        }
    }
    *(float4*)&out[(size_t)row * 32 + c4] = acc;
}

extern "C" void kernel_launch(void* const* d_in, const int* in_sizes, int n_in,
                              void* d_out, int out_size, void* d_ws, size_t ws_size,
                              hipStream_t stream) {
    const float* x      = (const float*)d_in[0];
    const int*   ei     = (const int*)d_in[1];
    const float* W1     = (const float*)d_in[2];
    const float* b1     = (const float*)d_in[3];
    const float* coeffs = (const float*)d_in[4];
    const float* W2     = (const float*)d_in[5];
    const float* b2     = (const float*)d_in[6];
    float* out = (float*)d_out;

    char* ws = (char*)d_ws;
    size_t off = 0;
    auto alloc = [&](size_t bytes) { void* p = ws + off; off += (bytes + 255) & ~(size_t)255; return p; };
    int*      cnt    = (int*)alloc(NN * 4);
    int*      cursor = (int*)alloc(NN * 4);
    int*      bsum   = (int*)alloc(NBLK * 4);
    float*    dinv   = (float*)alloc(NN * 4);
    int2*     csr    = (int2*)alloc((size_t)NE * 8);
    _Float16* W1T    = (_Float16*)alloc(256 * 64 * 2);
    __half*   h16    = (__half*)alloc((size_t)NN * HID * 2);
    __half*   bufA   = (__half*)alloc((size_t)NN * HID * 2);
    __half*   bufB   = (__half*)alloc((size_t)NN * HID * 2);
    __half*   bufC   = (__half*)alloc((size_t)NN * HID * 2);
    __half*   accb   = (__half*)alloc((size_t)NN * HID * 2);

    const int BN = (NN + 255) / 256;
    const int BE = (NE + 255) / 256;
    const int BP = (NN + 3) / 4;

    // --- CSR build ---
    k_zero<<<BN, 256, 0, stream>>>(cnt);
    k_hist<<<BE, 256, 0, stream>>>(ei, cnt);
    k_dinv<<<BN, 256, 0, stream>>>(cnt, dinv);
    k_scan1<<<NBLK, SCAN_BLK, 0, stream>>>(cnt, cursor, bsum);
    k_scan2<<<1, 64, 0, stream>>>(bsum);
    k_scan3<<<NBLK, SCAN_BLK, 0, stream>>>(cursor, bsum);
    k_scatter<<<BE, 256, 0, stream>>>(ei, dinv, cursor, csr);

    // --- h = relu(x @ W1 + b1) via MFMA ---
    k_prepw1<<<64, 256, 0, stream>>>(W1, W1T);
    k_gemm1<<<(NN + 63) / 64, 256, 0, stream>>>(x, W1T, b1, h16);

    __half* rot[4] = {h16, bufA, bufB, bufC};

    for (int l = 0; l < 2; ++l) {
        int cbase = l * (KORD + 1);
        k_prop<<<BP, 256, 0, stream>>>(cursor, csr, rot[0], rot[0], dinv,
                                       rot[1], accb, h16, 1.0f, 0.0f, 0.0f,
                                       coeffs, cbase, 1, 1, 0);
        for (int k = 2; k <= KORD; ++k) {
            __half* dst = rot[k & 3];
            const __half* s1 = rot[(k - 1) & 3];
            const __half* s0 = rot[(k - 2) & 3];
            double n = k - 1, a = 0.5, b = 0.5;
            double An = (2*n + a + b + 1) * (2*n + a + b + 2) / (2 * (n + 1) * (n + a + b + 1));
            double Bn = (a*a - b*b) * (2*n + a + b + 1) / (2 * (n + 1) * (n + a + b + 1) * (2*n + a + b));
            double Cn = (n + a) * (n + b) * (2*n + a + b + 2) / ((n + 1) * (n + a + b + 1) * (2*n + a + b));
            k_prop<<<BP, 256, 0, stream>>>(cursor, csr, s1, s0, dinv,
                                           dst, accb, h16, (float)An, (float)Bn, (float)Cn,
                                           coeffs, cbase, k, 0, (k == KORD) ? 1 : 0);
        }
    }

    // out = h @ W2 + b2
    k_gemm2<<<(NN * 8 + 255) / 256, 256, 0, stream>>>(h16, W2, b2, out);
}

// Round 6
// 1366.235 us; speedup vs baseline: 5.9295x; 1.0389x over previous
//
#include <hip/hip_runtime.h>
#include <hip/hip_fp16.h>

#define NN 100000
#define NE 1600000
#define KORD 10
#define HID 64
#define SCAN_BLK 1024
#define NBLK ((NN + SCAN_BLK - 1) / SCAN_BLK)   // 98

typedef _Float16 half8v __attribute__((ext_vector_type(8)));
typedef _Float16 half4v __attribute__((ext_vector_type(4)));
typedef float float4v __attribute__((ext_vector_type(4)));

__device__ __forceinline__ float2 up2(unsigned u) {
    __half2 hh = *(__half2*)&u;
    return __half22float2(hh);
}
__device__ __forceinline__ unsigned pk2(float a, float b) {
    __half2 hh = __floats2half2_rn(a, b);
    return *(unsigned*)&hh;
}

// ---------------- CSR build ----------------
__global__ __launch_bounds__(256) void k_zero(int* __restrict__ cnt) {
    int i = blockIdx.x * 256 + threadIdx.x;
    if (i < NN) cnt[i] = 0;
}

__global__ __launch_bounds__(256) void k_hist(const int* __restrict__ ei,
                                              int* __restrict__ cnt) {
    int e = blockIdx.x * 256 + threadIdx.x;
    if (e < NE) atomicAdd(&cnt[ei[NE + e]], 1);
}

__global__ __launch_bounds__(256) void k_dinv(const int* __restrict__ cnt,
                                              float* __restrict__ dinv) {
    int i = blockIdx.x * 256 + threadIdx.x;
    if (i < NN) dinv[i] = rsqrtf((float)(cnt[i] + 1));   // +1 self-loop
}

__global__ __launch_bounds__(SCAN_BLK) void k_scan1(const int* __restrict__ cnt,
                                                    int* __restrict__ cursor,
                                                    int* __restrict__ bsum) {
    __shared__ int tmp[SCAN_BLK];
    int t = threadIdx.x;
    int g = blockIdx.x * SCAN_BLK + t;
    int v = (g < NN) ? cnt[g] : 0;
    tmp[t] = v;
    __syncthreads();
    int x = v;
    for (int off = 1; off < SCAN_BLK; off <<= 1) {
        int y = (t >= off) ? tmp[t - off] : 0;
        __syncthreads();
        x += y;
        tmp[t] = x;
        __syncthreads();
    }
    if (g < NN) cursor[g] = x - v;
    if (t == SCAN_BLK - 1) bsum[blockIdx.x] = x;
}

// parallel exclusive scan of the 98 block sums
__global__ __launch_bounds__(128) void k_scan2(int* __restrict__ bsum) {
    __shared__ int tmp[128];
    int t = threadIdx.x;
    int v = (t < NBLK) ? bsum[t] : 0;
    tmp[t] = v;
    __syncthreads();
    int x = v;
    for (int off = 1; off < 128; off <<= 1) {
        int y = (t >= off) ? tmp[t - off] : 0;
        __syncthreads();
        x += y;
        tmp[t] = x;
        __syncthreads();
    }
    if (t < NBLK) bsum[t] = x - v;
}

__global__ __launch_bounds__(SCAN_BLK) void k_scan3(int* __restrict__ cursor,
                                                    const int* __restrict__ bsum) {
    int g = blockIdx.x * SCAN_BLK + threadIdx.x;
    if (g < NN) cursor[g] += bsum[blockIdx.x];
}

// weightless scatter: csr[pos] = source row only
__global__ __launch_bounds__(256) void k_scatter(const int* __restrict__ ei,
                                                 int* __restrict__ cursor,
                                                 int* __restrict__ csr) {
    int e = blockIdx.x * 256 + threadIdx.x;
    if (e >= NE) return;
    int r = ei[e], c = ei[NE + e];
    int pos = atomicAdd(&cursor[c], 1);
    csr[pos] = r;
}

// zero the sentinel row NN of the 4 rotation buffers (padded gathers land there)
__global__ __launch_bounds__(256) void k_zrow(__half* __restrict__ a, __half* __restrict__ b,
                                              __half* __restrict__ c, __half* __restrict__ d) {
    int t = threadIdx.x;
    __half z = __float2half(0.f);
    size_t base = (size_t)NN * HID;
    if (t < 64)       a[base + t] = z;
    else if (t < 128) b[base + (t - 64)] = z;
    else if (t < 192) c[base + (t - 128)] = z;
    else              d[base + (t - 192)] = z;
}

// ---------- W1 transpose + fp16 cast: W1T[n][k] = W1[k][n] ----------
__global__ __launch_bounds__(256) void k_prepw1(const float* __restrict__ W1,
                                                _Float16* __restrict__ W1T) {
    int f = blockIdx.x * 256 + threadIdx.x;   // 0..16383
    int n = f >> 8, k = f & 255;
    W1T[f] = (_Float16)W1[k * 64 + n];
}

// ---------- GEMM1 via MFMA: h~ = dinv * relu(x @ W1 + b1) (scaled features) ----------
#define G1K 128
#define G1S 136
__global__ __launch_bounds__(256) void k_gemm1(const float* __restrict__ x,
                                               const _Float16* __restrict__ W1T,
                                               const float* __restrict__ b1,
                                               const float* __restrict__ dinv,
                                               __half* __restrict__ h) {
    __shared__ _Float16 A_lds[64 * G1S];
    __shared__ _Float16 B_lds[64 * G1S];
    int t = threadIdx.x;
    int wave = t >> 6, lane = t & 63;
    int quad = lane >> 4, m16 = lane & 15;
    int row0 = blockIdx.x * 64;

    float4v acc[4];
#pragma unroll
    for (int n4 = 0; n4 < 4; ++n4) acc[n4] = (float4v){0.f, 0.f, 0.f, 0.f};

    for (int c = 0; c < 2; ++c) {
        int k0 = c * G1K;
#pragma unroll
        for (int i = 0; i < 8; ++i) {
            int f = i * 256 + t;
            int r = f >> 5, c4 = f & 31;
            int grow = row0 + r;
            float4 v = (grow < NN) ? *(const float4*)&x[(size_t)grow * 256 + k0 + c4 * 4]
                                   : make_float4(0.f, 0.f, 0.f, 0.f);
            half4v hv = {(_Float16)v.x, (_Float16)v.y, (_Float16)v.z, (_Float16)v.w};
            *(half4v*)&A_lds[r * G1S + c4 * 4] = hv;
        }
#pragma unroll
        for (int i = 0; i < 4; ++i) {
            int f = i * 256 + t;
            int n = f >> 4, k8 = f & 15;
            *(half8v*)&B_lds[n * G1S + k8 * 8] =
                *(const half8v*)&W1T[n * 256 + k0 + k8 * 8];
        }
        __syncthreads();

#pragma unroll
        for (int s = 0; s < 4; ++s) {
            half8v af = *(const half8v*)&A_lds[(wave * 16 + m16) * G1S + s * 32 + quad * 8];
#pragma unroll
            for (int n4 = 0; n4 < 4; ++n4) {
                half8v bf = *(const half8v*)&B_lds[(n4 * 16 + m16) * G1S + s * 32 + quad * 8];
                acc[n4] = __builtin_amdgcn_mfma_f32_16x16x32_f16(af, bf, acc[n4], 0, 0, 0);
            }
        }
        __syncthreads();
    }

    float bv[4];
#pragma unroll
    for (int n4 = 0; n4 < 4; ++n4) bv[n4] = b1[n4 * 16 + m16];
#pragma unroll
    for (int r = 0; r < 4; ++r) {
        int grow = row0 + wave * 16 + quad * 4 + r;
        if (grow >= NN) continue;
        float dv = dinv[grow];
#pragma unroll
        for (int n4 = 0; n4 < 4; ++n4) {
            float v = dv * fmaxf(acc[n4][r] + bv[n4], 0.f);
            h[(size_t)grow * 64 + n4 * 16 + m16] = __float2half(v);
        }
    }
}

// ---------- fused propagation + Jacobi combine on SCALED features ----------
// T~2[c] = An*dv^2*(sum_{r->c} T~1[r] + T~1[c]) + Bn*T~1[c] - Cn*T~0[c]
// One wave per node. sub = lane>>3 (edge in group of 8), ch8 = (lane&7)*8.
// 32 edges per loop iteration: 4 independent csr loads + 4 independent gathers.
__global__ __launch_bounds__(256) void k_prop(const int* __restrict__ cursor,   // end offsets
                                              const int* __restrict__ csr,
                                              const __half* __restrict__ src,
                                              const __half* __restrict__ t0,
                                              const float* __restrict__ dinv,
                                              __half* __restrict__ dst,
                                              __half* __restrict__ acc,
                                              __half* __restrict__ hout,
                                              float An, float Bn, float Cn,
                                              const float* __restrict__ coeffs,
                                              int cbase, int kidx, int init,
                                              int finalize, int unscale) {
    int node = blockIdx.x * 4 + (threadIdx.x >> 6);
    int lane = threadIdx.x & 63;
    if (node >= NN) return;

    int beg = (node == 0) ? 0 : cursor[node - 1];
    int end = cursor[node];

    int sub = lane >> 3;
    int ch8 = (lane & 7) * 8;

    float p[8];
#pragma unroll
    for (int i = 0; i < 8; ++i) p[i] = 0.f;

    for (int j = beg; j < end; j += 32) {
        int j0 = j + sub;
        int r0 = (j0      < end) ? csr[j0]      : NN;
        int r1 = (j0 + 8  < end) ? csr[j0 + 8]  : NN;
        int r2 = (j0 + 16 < end) ? csr[j0 + 16] : NN;
        int r3 = (j0 + 24 < end) ? csr[j0 + 24] : NN;
        uint4 raw0 = *(const uint4*)&src[(size_t)r0 * HID + ch8];
        uint4 raw1 = *(const uint4*)&src[(size_t)r1 * HID + ch8];
        uint4 raw2 = *(const uint4*)&src[(size_t)r2 * HID + ch8];
        uint4 raw3 = *(const uint4*)&src[(size_t)r3 * HID + ch8];
        {
            float2 f0 = up2(raw0.x), f1 = up2(raw0.y), f2 = up2(raw0.z), f3 = up2(raw0.w);
            p[0] += f0.x; p[1] += f0.y; p[2] += f1.x; p[3] += f1.y;
            p[4] += f2.x; p[5] += f2.y; p[6] += f3.x; p[7] += f3.y;
        }
        {
            float2 f0 = up2(raw1.x), f1 = up2(raw1.y), f2 = up2(raw1.z), f3 = up2(raw1.w);
            p[0] += f0.x; p[1] += f0.y; p[2] += f1.x; p[3] += f1.y;
            p[4] += f2.x; p[5] += f2.y; p[6] += f3.x; p[7] += f3.y;
        }
        {
            float2 f0 = up2(raw2.x), f1 = up2(raw2.y), f2 = up2(raw2.z), f3 = up2(raw2.w);
            p[0] += f0.x; p[1] += f0.y; p[2] += f1.x; p[3] += f1.y;
            p[4] += f2.x; p[5] += f2.y; p[6] += f3.x; p[7] += f3.y;
        }
        {
            float2 f0 = up2(raw3.x), f1 = up2(raw3.y), f2 = up2(raw3.z), f3 = up2(raw3.w);
            p[0] += f0.x; p[1] += f0.y; p[2] += f1.x; p[3] += f1.y;
            p[4] += f2.x; p[5] += f2.y; p[6] += f3.x; p[7] += f3.y;
        }
    }

#pragma unroll
    for (int m = 8; m <= 32; m <<= 1) {
#pragma unroll
        for (int i = 0; i < 8; ++i) p[i] += __shfl_xor(p[i], m);
    }

    if (sub != 0) return;
    size_t idx = (size_t)node * HID + ch8;
    float dv = dinv[node];
    float dv2 = dv * dv;

    uint4 sr = *(const uint4*)&src[idx];
    float2 s01 = up2(sr.x), s23 = up2(sr.y), s45 = up2(sr.z), s67 = up2(sr.w);
    float sv[8] = {s01.x, s01.y, s23.x, s23.y, s45.x, s45.y, s67.x, s67.y};

    uint4 tr = *(const uint4*)&t0[idx];
    float2 t01 = up2(tr.x), t23 = up2(tr.y), t45 = up2(tr.z), t67 = up2(tr.w);
    float tv[8] = {t01.x, t01.y, t23.x, t23.y, t45.x, t45.y, t67.x, t67.y};

    float v[8];
#pragma unroll
    for (int i = 0; i < 8; ++i)
        v[i] = An * dv2 * (p[i] + sv[i]) + Bn * sv[i] - Cn * tv[i];

    if (!finalize) {
        uint4 o;
        o.x = pk2(v[0], v[1]); o.y = pk2(v[2], v[3]);
        o.z = pk2(v[4], v[5]); o.w = pk2(v[6], v[7]);
        *(uint4*)&dst[idx] = o;
    }

    float ck = coeffs[cbase + kidx];
    float av[8];
    if (init) {
        float c0 = coeffs[cbase];
#pragma unroll
        for (int i = 0; i < 8; ++i) av[i] = c0 * sv[i];
    } else {
        uint4 ar = *(const uint4*)&acc[idx];
        float2 a01 = up2(ar.x), a23 = up2(ar.y), a45 = up2(ar.z), a67 = up2(ar.w);
        av[0] = a01.x; av[1] = a01.y; av[2] = a23.x; av[3] = a23.y;
        av[4] = a45.x; av[5] = a45.y; av[6] = a67.x; av[7] = a67.y;
    }
#pragma unroll
    for (int i = 0; i < 8; ++i) av[i] += ck * v[i];

    uint4 o;
    if (finalize) {
        // layer 0: h~_next = relu(acc~)  (scaling cancels)
        // layer 1: h_final = relu(acc~) / dv  (unscale for GEMM2)
        float s = unscale ? (1.0f / dv) : 1.0f;
        o.x = pk2(s * fmaxf(av[0], 0.f), s * fmaxf(av[1], 0.f));
        o.y = pk2(s * fmaxf(av[2], 0.f), s * fmaxf(av[3], 0.f));
        o.z = pk2(s * fmaxf(av[4], 0.f), s * fmaxf(av[5], 0.f));
        o.w = pk2(s * fmaxf(av[6], 0.f), s * fmaxf(av[7], 0.f));
        *(uint4*)&hout[idx] = o;
    } else {
        o.x = pk2(av[0], av[1]); o.y = pk2(av[2], av[3]);
        o.z = pk2(av[4], av[5]); o.w = pk2(av[6], av[7]);
        *(uint4*)&acc[idx] = o;
    }
}

// ---------- GEMM2: out = h16 @ W2 + b2 ----------
__global__ __launch_bounds__(256) void k_gemm2(const __half* __restrict__ h,
                                               const float* __restrict__ W2,
                                               const float* __restrict__ b2,
                                               float* __restrict__ out) {
    __shared__ float W2s[64 * 32];
    __shared__ float b2s[32];
    int t = threadIdx.x;
    for (int i = t * 4; i < 64 * 32; i += 256 * 4)
        *(float4*)&W2s[i] = *(const float4*)&W2[i];
    if (t < 32) b2s[t] = b2[t];
    __syncthreads();

    int gid = blockIdx.x * 256 + t;
    int row = gid >> 3;
    int c4 = (t & 7) * 4;
    if (row >= NN) return;
    const __half* hr = h + (size_t)row * 64;
    float4 acc = *(const float4*)&b2s[c4];
#pragma unroll
    for (int k8 = 0; k8 < 8; ++k8) {
        uint4 raw = *(const uint4*)&hr[k8 * 8];
        float2 a01 = up2(raw.x), a23 = up2(raw.y), a45 = up2(raw.z), a67 = up2(raw.w);
        float a[8] = {a01.x, a01.y, a23.x, a23.y, a45.x, a45.y, a67.x, a67.y};
#pragma unroll
        for (int j = 0; j < 8; ++j) {
            float4 w = *(const float4*)&W2s[(k8 * 8 + j) * 32 + c4];
            acc.x += a[j] * w.x;
            acc.y += a[j] * w.y;
            acc.z += a[j] * w.z;
            acc.w += a[j] * w.w;
        }
    }
    *(float4*)&out[(size_t)row * 32 + c4] = acc;
}

extern "C" void kernel_launch(void* const* d_in, const int* in_sizes, int n_in,
                              void* d_out, int out_size, void* d_ws, size_t ws_size,
                              hipStream_t stream) {
    const float* x      = (const float*)d_in[0];
    const int*   ei     = (const int*)d_in[1];
    const float* W1     = (const float*)d_in[2];
    const float* b1     = (const float*)d_in[3];
    const float* coeffs = (const float*)d_in[4];
    const float* W2     = (const float*)d_in[5];
    const float* b2     = (const float*)d_in[6];
    float* out = (float*)d_out;

    char* ws = (char*)d_ws;
    size_t off = 0;
    auto alloc = [&](size_t bytes) { void* p = ws + off; off += (bytes + 255) & ~(size_t)255; return p; };
    int*      cnt    = (int*)alloc(NN * 4);
    int*      cursor = (int*)alloc(NN * 4);
    int*      bsum   = (int*)alloc(NBLK * 4);
    float*    dinv   = (float*)alloc(NN * 4);
    int*      csr    = (int*)alloc((size_t)NE * 4);
    _Float16* W1T    = (_Float16*)alloc(256 * 64 * 2);
    __half*   h16    = (__half*)alloc((size_t)(NN + 1) * HID * 2);   // +1 sentinel row
    __half*   bufA   = (__half*)alloc((size_t)(NN + 1) * HID * 2);
    __half*   bufB   = (__half*)alloc((size_t)(NN + 1) * HID * 2);
    __half*   bufC   = (__half*)alloc((size_t)(NN + 1) * HID * 2);
    __half*   accb   = (__half*)alloc((size_t)NN * HID * 2);

    const int BN = (NN + 255) / 256;
    const int BE = (NE + 255) / 256;
    const int BP = (NN + 3) / 4;

    // --- CSR build ---
    k_zero<<<BN, 256, 0, stream>>>(cnt);
    k_hist<<<BE, 256, 0, stream>>>(ei, cnt);
    k_dinv<<<BN, 256, 0, stream>>>(cnt, dinv);
    k_scan1<<<NBLK, SCAN_BLK, 0, stream>>>(cnt, cursor, bsum);
    k_scan2<<<1, 128, 0, stream>>>(bsum);
    k_scan3<<<NBLK, SCAN_BLK, 0, stream>>>(cursor, bsum);
    k_scatter<<<BE, 256, 0, stream>>>(ei, cursor, csr);
    k_zrow<<<1, 256, 0, stream>>>(h16, bufA, bufB, bufC);

    // --- h~ = dinv * relu(x @ W1 + b1) via MFMA ---
    k_prepw1<<<64, 256, 0, stream>>>(W1, W1T);
    k_gemm1<<<(NN + 63) / 64, 256, 0, stream>>>(x, W1T, b1, dinv, h16);

    __half* rot[4] = {h16, bufA, bufB, bufC};

    for (int l = 0; l < 2; ++l) {
        int cbase = l * (KORD + 1);
        k_prop<<<BP, 256, 0, stream>>>(cursor, csr, rot[0], rot[0], dinv,
                                       rot[1], accb, h16, 1.0f, 0.0f, 0.0f,
                                       coeffs, cbase, 1, 1, 0, 0);
        for (int k = 2; k <= KORD; ++k) {
            __half* dst = rot[k & 3];
            const __half* s1 = rot[(k - 1) & 3];
            const __half* s0 = rot[(k - 2) & 3];
            double n = k - 1, a = 0.5, b = 0.5;
            double An = (2*n + a + b + 1) * (2*n + a + b + 2) / (2 * (n + 1) * (n + a + b + 1));
            double Bn = (a*a - b*b) * (2*n + a + b + 1) / (2 * (n + 1) * (n + a + b + 1) * (2*n + a + b));
            double Cn = (n + a) * (n + b) * (2*n + a + b + 2) / ((n + 1) * (n + a + b + 1) * (2*n + a + b));
            k_prop<<<BP, 256, 0, stream>>>(cursor, csr, s1, s0, dinv,
                                           dst, accb, h16, (float)An, (float)Bn, (float)Cn,
                                           coeffs, cbase, k, 0,
                                           (k == KORD) ? 1 : 0, l);
        }
    }

    // out = h @ W2 + b2
    k_gemm2<<<(NN * 8 + 255) / 256, 256, 0, stream>>>(h16, W2, b2, out);
}